// Round 5
// baseline (176.944 us; speedup 1.0000x reference)
//
#include <hip/hip_runtime.h>
#include <math.h>
#include <stdint.h>

#define PI_F 3.14159265358979323846f
#define HALF_PI_F 1.57079632679489662f

// Problem constants: B=32, N=200000, H=1024, W=2048
#define IMG_H 1024
#define IMG_W 2048
#define NB 8          // batches per thread
#define NBINS_T 128   // theta bins
#define NBINS_P 64    // phi bins
#define NBINS (NBINS_T * NBINS_P)

// Workspace layout (bytes):
//   0       .. 2048        : rm (288 f) | sums (32 f @ float idx 288) | cnts (32 f @ 320)
//   2048    .. 2048+32768  : hist u32[8192] (counts -> offsets -> cursors)
//   65536   .. 65536+4MB   : pk: row-pair RGB565, u32 word[(y>>1)*2048+x] = lo:row 2p, hi:row 2p+1
//   65536+4MB .. +4.8MB    : pts: sorted points, 6 floats/pt {x,y,z,r,g,b}
#define HIST_OFF  2048
#define PK_OFF    65536
#define PTS_OFF   (65536 + 4 * 1024 * 1024)

__device__ __forceinline__ float fast_atan2f(float y, float x) {
    float ax = fabsf(x), ay = fabsf(y);
    float mx = fmaxf(ax, ay), mn = fminf(ax, ay);
    float a = __fdividef(mn, mx);
    float s = a * a;
    float r = fmaf(s, -0.01172120f, 0.05265332f);
    r = fmaf(s, r, -0.11643287f);
    r = fmaf(s, r, 0.19354346f);
    r = fmaf(s, r, -0.33262347f);
    r = fmaf(s, r, 0.99997726f);
    r = r * a;
    if (ay > ax) r = HALF_PI_F - r;
    if (x < 0.0f) r = PI_F - r;
    return copysignf(r, y);
}

__device__ __forceinline__ int dir_key(float x, float y, float z) {
    float theta = fast_atan2f(sqrtf(x * x + y * y), z);   // [0, pi]
    float phi   = fast_atan2f(y, x);                      // (-pi, pi]
    int tb = min(max((int)(theta * ((float)NBINS_T / PI_F)), 0), NBINS_T - 1);
    int pb = min(max((int)((phi + PI_F) * ((float)NBINS_P / (2.0f * PI_F))), 0), NBINS_P - 1);
    return tb * NBINS_P + pb;
}

__device__ __forceinline__ uint32_t quant565(const float* __restrict__ img, int pix) {
    float r = img[pix + 0], g = img[pix + 1], b = img[pix + 2];
    uint32_t r5 = min((uint32_t)__float2uint_rn(r * 31.0f), 31u);
    uint32_t g6 = min((uint32_t)__float2uint_rn(g * 63.0f), 63u);
    uint32_t b5 = min((uint32_t)__float2uint_rn(b * 31.0f), 31u);
    return (r5 << 11) | (g6 << 5) | b5;
}

// K1: blocks [0,4096): pack image to row-pair RGB565 (4MB).
//     blocks [4096,...): per-point bucket histogram; block 4096 also does Rm/sums/cnts setup.
__global__ __launch_bounds__(256) void bsl_pack_hist(
        const float* __restrict__ img, uint32_t* __restrict__ pk,
        const float* __restrict__ xyz, uint32_t* __restrict__ hist,
        const float* __restrict__ yaw, const float* __restrict__ pitch,
        const float* __restrict__ roll, float* __restrict__ rm,
        float* __restrict__ sums, float* __restrict__ cnts,
        int B, int n_pts) {
    const int bx = blockIdx.x;
    const int tid = threadIdx.x;
    if (bx < 4096) {
        int idx = bx * 256 + tid;          // word index: p*2048 + x, p in [0,512)
        int p = idx >> 11;
        int x = idx & (IMG_W - 1);
        uint32_t lo = quant565(img, ((2 * p) * IMG_W + x) * 3);
        uint32_t hi = quant565(img, ((2 * p + 1) * IMG_W + x) * 3);
        pk[idx] = lo | (hi << 16);
        return;
    }
    if (bx == 4096 && tid < 32) {
        int b = tid;
        if (b < B) {
            float cr = cosf(roll[b]),  sr = sinf(roll[b]);
            float cp = cosf(pitch[b]), sp = sinf(pitch[b]);
            float cy = cosf(yaw[b]),   sy = sinf(yaw[b]);
            float RX[9] = {1.f, 0.f, 0.f,   0.f, cr, -sr,   0.f, sr,  cr};
            float RY[9] = {cp,  0.f, sp,    0.f, 1.f, 0.f,  -sp, 0.f, cp};
            float RZ[9] = {cy, -sy, 0.f,    sy,  cy, 0.f,   0.f, 0.f, 1.f};
            float A[9], M[9];
            for (int i = 0; i < 3; ++i)
                for (int j = 0; j < 3; ++j) {
                    float s = 0.f;
                    for (int k = 0; k < 3; ++k) s += RZ[i*3+k] * RY[k*3+j];
                    A[i*3+j] = s;
                }
            for (int i = 0; i < 3; ++i)
                for (int j = 0; j < 3; ++j) {
                    float s = 0.f;
                    for (int k = 0; k < 3; ++k) s += A[i*3+k] * RX[k*3+j];
                    M[i*3+j] = s;
                }
            for (int k = 0; k < 9; ++k) rm[b*9+k] = M[k];
            sums[b] = 0.f;
            cnts[b] = 0.f;
        }
    }
    int n = (bx - 4096) * 256 + tid;
    if (n < n_pts) {
        int k = dir_key(xyz[3*n+0], xyz[3*n+1], xyz[3*n+2]);
        atomicAdd(&hist[k], 1u);
    }
}

// K2: exclusive prefix sum over 8192 bins, single block of 256 threads (32 bins each).
__global__ __launch_bounds__(256) void bsl_scan(uint32_t* __restrict__ hist) {
    __shared__ uint32_t part[256];
    int t = threadIdx.x;
    uint32_t local[32];
    uint32_t s = 0;
    #pragma unroll
    for (int i = 0; i < 32; ++i) { local[i] = hist[t * 32 + i]; s += local[i]; }
    part[t] = s;
    __syncthreads();
    // Hillis-Steele inclusive scan over the 256 partials
    for (int off = 1; off < 256; off <<= 1) {
        uint32_t v = (t >= off) ? part[t - off] : 0u;
        __syncthreads();
        part[t] += v;
        __syncthreads();
    }
    uint32_t run = (t == 0) ? 0u : part[t - 1];
    #pragma unroll
    for (int i = 0; i < 32; ++i) { uint32_t c = local[i]; hist[t * 32 + i] = run; run += c; }
}

// K3: scatter points into bucket-sorted order (recomputes the key; hist = cursors).
__global__ __launch_bounds__(256) void bsl_scatter(
        const float* __restrict__ xyz, const float* __restrict__ rgb,
        uint32_t* __restrict__ hist, float* __restrict__ pts, int n_pts) {
    int n = blockIdx.x * 256 + threadIdx.x;
    if (n >= n_pts) return;
    float x = xyz[3*n+0], y = xyz[3*n+1], z = xyz[3*n+2];
    int k = dir_key(x, y, z);
    uint32_t pos = atomicAdd(&hist[k], 1u);
    float* p = pts + (size_t)pos * 6;
    p[0] = x; p[1] = y; p[2] = z;
    p[3] = rgb[3*n+0]; p[4] = rgb[3*n+1]; p[5] = rgb[3*n+2];
}

__global__ __launch_bounds__(256) void bsl_main(
        const float* __restrict__ pts,
        const uint32_t* __restrict__ pk,
        const float* __restrict__ trans,
        const float* __restrict__ rm,
        float* __restrict__ sums,
        float* __restrict__ cnts,
        int n_pts) {
    const int b0 = blockIdx.y * NB;
    const int tid = threadIdx.x;
    const int n = blockIdx.x * 256 + tid;

    float accs[NB], cnl[NB];
    #pragma unroll
    for (int nb = 0; nb < NB; ++nb) { accs[nb] = 0.f; cnl[nb] = 0.f; }

    if (n < n_pts) {
        const float* P = pts + (size_t)n * 6;
        float px = __builtin_nontemporal_load(&P[0]);
        float py = __builtin_nontemporal_load(&P[1]);
        float pz = __builtin_nontemporal_load(&P[2]);
        float r0 = __builtin_nontemporal_load(&P[3]);
        float r1 = __builtin_nontemporal_load(&P[4]);
        float r2 = __builtin_nontemporal_load(&P[5]);

        #pragma unroll
        for (int nb = 0; nb < NB; ++nb) {
            const int b = b0 + nb;
            const float* R = rm + b * 9;        // block-uniform -> s_load
            const float* T = trans + b * 3;
            float qx = px - T[0], qy = py - T[1], qz = pz - T[2];

            float vx = R[0]*qx + R[1]*qy + R[2]*qz;
            float vy = R[3]*qx + R[4]*qy + R[5]*qz;
            float vz = R[6]*qx + R[7]*qy + R[8]*qz;

            float rxy   = sqrtf(vx*vx + vy*vy);
            float theta = fast_atan2f(rxy, vz);     // [0, pi]
            float praw  = fast_atan2f(vy, vx);      // (-pi, pi]

            // xf = 1023.5 - 1024*praw/pi ; yf = 1024*theta/pi - 0.5
            float xf = fmaf(praw,  -325.949323452f, 1023.5f);
            float yf = fmaf(theta,  325.949323452f, -0.5f);

            float x0f = floorf(xf), y0f = floorf(yf);
            float wx = xf - x0f, wy = yf - y0f;
            int x0 = (int)x0f, y0 = (int)y0f;
            int x1 = x0 + 1, y1 = y0 + 1;

            bool vx0 = (x0 >= 0) & (x0 <= IMG_W - 1);
            bool vx1 = (x1 >= 0) & (x1 <= IMG_W - 1);
            bool vy0 = (y0 >= 0) & (y0 <= IMG_H - 1);
            bool vy1 = (y1 >= 0) & (y1 <= IMG_H - 1);
            float w00 = (vx0 & vy0) ? (1.0f - wx) * (1.0f - wy) : 0.0f;
            float w10 = (vx1 & vy0) ? wx * (1.0f - wy) : 0.0f;
            float w01 = (vx0 & vy1) ? (1.0f - wx) * wy : 0.0f;
            float w11 = (vx1 & vy1) ? wx * wy : 0.0f;

            int x0c = min(max(x0, 0), IMG_W - 1);
            int x1c = min(max(x1, 0), IMG_W - 1);
            int y0c = min(max(y0, 0), IMG_H - 1);
            int y1c = min(max(y1, 0), IMG_H - 1);

            // 4MB row-pair layout, pure u32 index math.
            // Corner pairs (x0c,x1c) share a 64B line p=15/16; when y0c is even
            // the bottom words equal the top words (L1 hits).
            uint32_t rowA = ((uint32_t)(y0c >> 1)) << 11;
            uint32_t rowB = ((uint32_t)(y1c >> 1)) << 11;
            uint32_t wA = pk[rowA + (uint32_t)x0c];
            uint32_t wB = pk[rowA + (uint32_t)x1c];
            uint32_t wC = pk[rowB + (uint32_t)x0c];
            uint32_t wD = pk[rowB + (uint32_t)x1c];
            uint32_t t00 = (y0c & 1) ? (wA >> 16) : (wA & 0xffffu);
            uint32_t t10 = (y0c & 1) ? (wB >> 16) : (wB & 0xffffu);
            uint32_t t01 = (y1c & 1) ? (wC >> 16) : (wC & 0xffffu);
            uint32_t t11 = (y1c & 1) ? (wD >> 16) : (wD & 0xffffu);

            float s0 = (float)(t00 >> 11) * (1.0f/31.0f) * w00 + (float)(t10 >> 11) * (1.0f/31.0f) * w10
                     + (float)(t01 >> 11) * (1.0f/31.0f) * w01 + (float)(t11 >> 11) * (1.0f/31.0f) * w11;
            float s1 = (float)((t00 >> 5) & 63u) * (1.0f/63.0f) * w00 + (float)((t10 >> 5) & 63u) * (1.0f/63.0f) * w10
                     + (float)((t01 >> 5) & 63u) * (1.0f/63.0f) * w01 + (float)((t11 >> 5) & 63u) * (1.0f/63.0f) * w11;
            float s2 = (float)(t00 & 31u) * (1.0f/31.0f) * w00 + (float)(t10 & 31u) * (1.0f/31.0f) * w10
                     + (float)(t01 & 31u) * (1.0f/31.0f) * w01 + (float)(t11 & 31u) * (1.0f/31.0f) * w11;

            bool m = !((s0 == 0.0f) && (s1 == 0.0f) && (s2 == 0.0f));

            float d0 = s0 - r0;
            float d1 = s1 - r1;
            float d2 = s2 - r2;
            float per = sqrtf(d0*d0 + d1*d1 + d2*d2);

            accs[nb] += m ? per : 0.0f;
            cnl[nb]  += m ? 1.0f : 0.0f;
        }
    }

    // wave(64) shuffle reduce per batch, then LDS across 4 waves, then atomics
    __shared__ float lsum[4][NB], lcnt[4][NB];
    int wid = tid >> 6;
    int lane = tid & 63;
    #pragma unroll
    for (int nb = 0; nb < NB; ++nb) {
        float a = accs[nb], c = cnl[nb];
        #pragma unroll
        for (int off = 32; off > 0; off >>= 1) {
            a += __shfl_down(a, off, 64);
            c += __shfl_down(c, off, 64);
        }
        if (lane == 0) { lsum[wid][nb] = a; lcnt[wid][nb] = c; }
    }
    __syncthreads();
    if (tid < NB * 2) {
        int nb = tid & (NB - 1);
        int k = tid >> 3;   // 0 = sum, 1 = cnt
        float v = 0.f;
        #pragma unroll
        for (int w = 0; w < 4; ++w) v += k ? lcnt[w][nb] : lsum[w][nb];
        atomicAdd(k ? &cnts[b0 + nb] : &sums[b0 + nb], v);
    }
}

__global__ void bsl_finalize(const float* __restrict__ sums,
                             const float* __restrict__ cnts,
                             float* __restrict__ out,
                             int B) {
    int b = threadIdx.x;  // 0..63
    float loss = 0.f;
    if (b < B) {
        loss = sums[b] / cnts[b];
        out[1 + b] = loss;
    }
    #pragma unroll
    for (int off = 32; off > 0; off >>= 1)
        loss += __shfl_down(loss, off, 64);
    if (b == 0) out[0] = loss;
}

extern "C" void kernel_launch(void* const* d_in, const int* in_sizes, int n_in,
                              void* d_out, int out_size, void* d_ws, size_t ws_size,
                              hipStream_t stream) {
    const float* xyz   = (const float*)d_in[0];
    const float* rgb   = (const float*)d_in[1];
    const float* img   = (const float*)d_in[2];
    const float* trans = (const float*)d_in[3];
    const float* yaw   = (const float*)d_in[4];
    const float* pitch = (const float*)d_in[5];
    const float* roll  = (const float*)d_in[6];
    float* out = (float*)d_out;

    const int n_pts = in_sizes[0] / 3;      // 200000
    const int B     = in_sizes[3] / 3;      // 32

    float* ws    = (float*)d_ws;
    float* rm    = ws;               // 9*B floats
    float* sums  = ws + 9 * B;       // B floats
    float* cnts  = ws + 10 * B;      // B floats
    uint32_t* hist = (uint32_t*)((char*)d_ws + HIST_OFF);
    uint32_t* pk   = (uint32_t*)((char*)d_ws + PK_OFF);
    float*    pts  = (float*)((char*)d_ws + PTS_OFF);

    hipMemsetAsync(hist, 0, NBINS * sizeof(uint32_t), stream);

    const int key_blocks = (n_pts + 255) / 256;   // 782
    bsl_pack_hist<<<4096 + key_blocks, 256, 0, stream>>>(
        img, pk, xyz, hist, yaw, pitch, roll, rm, sums, cnts, B, n_pts);

    bsl_scan<<<1, 256, 0, stream>>>(hist);

    bsl_scatter<<<key_blocks, 256, 0, stream>>>(xyz, rgb, hist, pts, n_pts);

    dim3 grid(key_blocks, B / NB);
    bsl_main<<<grid, 256, 0, stream>>>(pts, pk, trans, rm, sums, cnts, n_pts);

    bsl_finalize<<<1, 64, 0, stream>>>(sums, cnts, out, B);
}